// Round 1
// baseline (49.370 us; speedup 1.0000x reference)
//
#include <hip/hip_runtime.h>
#include <math.h>

#define NB     4096   // batch rows
#define T      628    // slice length
#define LW     64     // shapelet length
#define NW     565    // T - LW + 1 windows
#define EW     128    // output embedding
#define XSTRIDE 8192  // C * LEN_TS
#define XOFF    2048  // DIM * LEN_TS

// ws layout: [0..127] combined bias  b1[e] - (shapelet . W2[e] + b2[e]);  ws[128] = s_ci
__global__ void prep_kernel(const float* __restrict__ shapelet,
                            const float* __restrict__ b1,
                            const float* __restrict__ W2,
                            const float* __restrict__ b2,
                            float* __restrict__ ws) {
    int e = threadIdx.x;
    if (e < EW) {
        float acc = 0.f;
        #pragma unroll
        for (int j = 0; j < LW; ++j) acc += shapelet[j] * W2[e * LW + j];
        ws[e] = b1[e] - (acc + b2[e]);
    }
    if (e == 0) {
        float s = 0.f;
        for (int j = 0; j < LW - 1; ++j) {
            float d = shapelet[j + 1] - shapelet[j];
            s += d * d;
        }
        ws[EW] = sqrtf(s + 0.001f);
    }
}

__global__ __launch_bounds__(256) void shapeblock_kernel(
        const float* __restrict__ x,
        const float* __restrict__ shapelet,
        const float* __restrict__ W1,
        const float* __restrict__ ws,
        float* __restrict__ out) {
    __shared__ float sp[T];
    __shared__ float sh[LW];
    __shared__ unsigned long long red[256];

    const int b   = blockIdx.x;
    const int tid = threadIdx.x;

    const float* xr = x + (size_t)b * XSTRIDE + XOFF;
    for (int i = tid; i < T; i += 256) sp[i] = xr[i];
    if (tid < LW) sh[tid] = shapelet[tid];
    const float s_ci = ws[EW];
    __syncthreads();

    // each thread: windows tid, tid+256, tid+512 (w < 565)
    unsigned long long key = ~0ull;
    for (int w = tid; w < NW; w += 256) {
        // windowed sum of squared first differences (63 terms)
        float sd = 0.f;
        #pragma unroll
        for (int j = 0; j < LW - 1; ++j) {
            float d = sp[w + j + 1] - sp[w + j];
            sd += d * d;
        }
        float pci = sqrtf(sd + 0.001f);

        // euclidean distance to shapelet (64 terms)
        float ed2 = 0.f;
        #pragma unroll
        for (int j = 0; j < LW; ++j) {
            float d = sp[w + j] - sh[j];
            ed2 += d * d;
        }
        float ed = sqrtf(ed2);

        float cf  = fminf(fmaxf(pci, s_ci) / fminf(pci, s_ci), 3.0f);
        float cid = ed * cf;

        // positive float: bit pattern is order-preserving. (bits<<32)|w gives
        // min-value with first-occurrence (smallest w) tie-break, exactly
        // matching jnp.argmin semantics.
        unsigned long long k =
            ((unsigned long long)__float_as_uint(cid) << 32) | (unsigned)w;
        if (k < key) key = k;
    }

    red[tid] = key;
    __syncthreads();
    #pragma unroll
    for (int s = 128; s > 0; s >>= 1) {
        if (tid < s) {
            unsigned long long o = red[tid + s];
            if (o < red[tid]) red[tid] = o;
        }
        __syncthreads();
    }
    const int widx = (int)(red[0] & 0xffffffffu);

    // GEMV: out[b][e] = sum_j window[j] * W1[e][j] + (b1[e] - out_s[e])
    if (tid < EW) {
        float acc = ws[tid];
        const float* wrow = W1 + tid * LW;
        #pragma unroll
        for (int j = 0; j < LW; ++j) acc += sp[widx + j] * wrow[j];
        out[(size_t)b * EW + tid] = acc;
    }
}

extern "C" void kernel_launch(void* const* d_in, const int* in_sizes, int n_in,
                              void* d_out, int out_size, void* d_ws, size_t ws_size,
                              hipStream_t stream) {
    const float* x        = (const float*)d_in[0];
    const float* shapelet = (const float*)d_in[1];
    const float* W1       = (const float*)d_in[2];
    const float* b1       = (const float*)d_in[3];
    const float* W2       = (const float*)d_in[4];
    const float* b2       = (const float*)d_in[5];
    float* out = (float*)d_out;
    float* ws  = (float*)d_ws;

    prep_kernel<<<1, 128, 0, stream>>>(shapelet, b1, W2, b2, ws);
    shapeblock_kernel<<<NB, 256, 0, stream>>>(x, shapelet, W1, ws, out);
}

// Round 2
// 44.948 us; speedup vs baseline: 1.0984x; 1.0984x over previous
//
#include <hip/hip_runtime.h>
#include <math.h>

#define NB      4096   // batch rows
#define T       628    // slice length
#define LW      64     // shapelet length
#define NW      565    // T - LW + 1 windows
#define EW      128    // output embedding
#define XSTRIDE 8192   // C * LEN_TS
#define XOFF    2048   // DIM * LEN_TS
#define WPT     9      // windows per thread (64*9 = 576 >= 565)
#define SPPAD   640    // sp padded length (max read index 639)

// ws float layout:
//   [0..127]   combined bias: b1[e] - (shapelet . W2[e] + b2[e])
//   [128]      s_ci = sqrt(sum(diff(shapelet)^2) + 1e-3)
//   [129]      ss2  = sum(shapelet^2)
//   [132..132+8191]  W1T[j*128 + e] = W1[e*64 + j]   (only if ws big enough)
#define WS_SCI 128
#define WS_SS2 129
#define WS_W1T 132
#define WS_NEEDED ((WS_W1T + EW * LW) * sizeof(float))

__global__ void prep_kernel(const float* __restrict__ shapelet,
                            const float* __restrict__ b1,
                            const float* __restrict__ W1,
                            const float* __restrict__ W2,
                            const float* __restrict__ b2,
                            float* __restrict__ ws, int use_wt) {
    int tid = threadIdx.x;  // 256 threads
    if (tid < EW) {
        float acc = 0.f;
        #pragma unroll
        for (int j = 0; j < LW; ++j) acc += shapelet[j] * W2[tid * LW + j];
        ws[tid] = b1[tid] - (acc + b2[tid]);
    }
    if (tid == 0) {
        float s = 0.f, q = 0.f;
        for (int j = 0; j < LW - 1; ++j) {
            float d = shapelet[j + 1] - shapelet[j];
            s += d * d;
        }
        for (int j = 0; j < LW; ++j) q += shapelet[j] * shapelet[j];
        ws[WS_SCI] = sqrtf(s + 0.001f);
        ws[WS_SS2] = q;
    }
    if (use_wt) {
        for (int idx = tid; idx < EW * LW; idx += 256) {
            int e = idx & (EW - 1);
            int j = idx >> 7;
            ws[WS_W1T + idx] = W1[e * LW + j];
        }
    }
}

__global__ __launch_bounds__(64) void shapeblock_kernel(
        const float* __restrict__ x,
        const float* __restrict__ shapelet,
        const float* __restrict__ W1,
        const float* __restrict__ ws,
        float* __restrict__ out, int use_wt) {
    __shared__ __align__(16) float sp[SPPAD];
    __shared__ float sh[LW];

    const int b   = blockIdx.x;
    const int tid = threadIdx.x;  // 0..63, one wave

    // ---- stage row (628 floats = 157 float4, coalesced) ----
    const float4* xr4 = (const float4*)(x + (size_t)b * XSTRIDE + XOFF);
    float4* sp4 = (float4*)sp;
    #pragma unroll
    for (int i = tid; i < T / 4; i += 64) sp4[i] = xr4[i];
    if (tid < SPPAD - T) sp[T + tid] = 0.f;      // zero pad 628..639
    sh[tid] = shapelet[tid];
    const float s_ci = ws[WS_SCI];
    const float ss2  = ws[WS_SS2];
    __syncthreads();

    const int w0 = tid * WPT;

    // ---- cross-correlation for WPT windows via register ring ----
    float ring[WPT];
    float acc[WPT];
    #pragma unroll
    for (int i = 0; i < WPT; ++i) { ring[i] = sp[w0 + i]; acc[i] = 0.f; }
    #pragma unroll 64
    for (int j = 0; j < LW; ++j) {
        const float sj = sh[j];
        #pragma unroll
        for (int i = 0; i < WPT; ++i)
            acc[i] = fmaf(ring[(j + i) % WPT], sj, acc[i]);
        if (j < LW - 1) ring[j % WPT] = sp[w0 + j + WPT];
    }

    // ---- first-window CI sum and sum-of-squares ----
    float sd = 0.f, sw2 = 0.f;
    {
        float prev = sp[w0];
        #pragma unroll
        for (int j = 1; j < LW; ++j) {
            float cur = sp[w0 + j];
            float d = cur - prev;
            sd = fmaf(d, d, sd);
            prev = cur;
        }
        #pragma unroll
        for (int j = 0; j < LW; ++j) {
            float v = sp[w0 + j];
            sw2 = fmaf(v, v, sw2);
        }
    }

    // ---- per-window CID + argmin key; O(1) slide updates ----
    unsigned long long key = ~0ull;
    #pragma unroll
    for (int k = 0; k < WPT; ++k) {
        const int w = w0 + k;
        float pci = sqrtf(sd + 0.001f);
        float ed2 = fmaxf(fmaf(-2.f, acc[k], sw2 + ss2), 0.f);
        float ed  = sqrtf(ed2);
        float cf  = fminf(fmaxf(pci, s_ci) / fminf(pci, s_ci), 3.0f);
        float cid = ed * cf;
        if (w < NW) {
            unsigned long long kk =
                ((unsigned long long)__float_as_uint(cid) << 32) | (unsigned)w;
            key = kk < key ? kk : key;
        }
        // slide to window w+1
        float dold = sp[w + 1]  - sp[w];
        float dnew = sp[w + 64] - sp[w + 63];
        sd  = fmaf(dnew, dnew, fmaf(-dold, dold, sd));
        float vold = sp[w], vnew = sp[w + 64];
        sw2 = fmaf(vnew, vnew, fmaf(-vold, vold, sw2));
    }

    // ---- wave argmin (butterfly; all lanes converge to min key) ----
    #pragma unroll
    for (int off = 32; off > 0; off >>= 1) {
        unsigned long long o =
            (unsigned long long)__shfl_xor((long long)key, off, 64);
        key = o < key ? o : key;
    }
    const int widx = (int)(key & 0xffffffffu);

    // ---- GEMV: out[b][e] = window . W1[e] + bias[e], e = tid, tid+64 ----
    float a0 = ws[tid];
    float a1 = ws[tid + 64];
    if (use_wt) {
        const float* wt = ws + WS_W1T;
        #pragma unroll
        for (int j = 0; j < LW; ++j) {
            float wv = sp[widx + j];              // broadcast
            a0 = fmaf(wv, wt[j * EW + tid], a0);       // coalesced
            a1 = fmaf(wv, wt[j * EW + 64 + tid], a1);
        }
    } else {
        #pragma unroll
        for (int j = 0; j < LW; ++j) {
            float wv = sp[widx + j];
            a0 = fmaf(wv, W1[tid * LW + j], a0);
            a1 = fmaf(wv, W1[(tid + 64) * LW + j], a1);
        }
    }
    out[(size_t)b * EW + tid]      = a0;
    out[(size_t)b * EW + tid + 64] = a1;
}

extern "C" void kernel_launch(void* const* d_in, const int* in_sizes, int n_in,
                              void* d_out, int out_size, void* d_ws, size_t ws_size,
                              hipStream_t stream) {
    const float* x        = (const float*)d_in[0];
    const float* shapelet = (const float*)d_in[1];
    const float* W1       = (const float*)d_in[2];
    const float* b1       = (const float*)d_in[3];
    const float* W2       = (const float*)d_in[4];
    const float* b2       = (const float*)d_in[5];
    float* out = (float*)d_out;
    float* ws  = (float*)d_ws;

    const int use_wt = (ws_size >= WS_NEEDED) ? 1 : 0;

    prep_kernel<<<1, 256, 0, stream>>>(shapelet, b1, W1, W2, b2, ws, use_wt);
    shapeblock_kernel<<<NB, 64, 0, stream>>>(x, shapelet, W1, ws, out, use_wt);
}

// Round 3
// 42.704 us; speedup vs baseline: 1.1561x; 1.0525x over previous
//
#include <hip/hip_runtime.h>
#include <math.h>

#define NB      4096   // batch rows
#define T       628    // slice length
#define LW      64     // shapelet length
#define NW      565    // T - LW + 1 windows
#define EW      128    // output embedding
#define XSTRIDE 8192   // C * LEN_TS
#define XOFF    2048   // DIM * LEN_TS
#define WPT     9      // windows per thread (64*9 = 576 >= 565)
#define SPPAD   640    // padded row length (max read index 638)

// ws float layout:
//   [0..127]  combined bias: b1[e] - (shapelet . W2[e] + b2[e])
//   [128]     s_ci   [129] ss2 = sum(shapelet^2)
//   [132..]   W1T[j*128 + e] = W1[e*64 + j]
#define WS_SCI 128
#define WS_SS2 129
#define WS_W1T 132
#define WS_NEEDED ((WS_W1T + EW * LW) * sizeof(float))

// 129 one-wave blocks: block e<128 handles output e (coalesced row reads,
// shfl-reduce dot, scattered single-column W1T write); block 128 does s_ci/ss2.
__global__ __launch_bounds__(64) void prep_kernel(
        const float* __restrict__ shapelet,
        const float* __restrict__ b1,
        const float* __restrict__ W1,
        const float* __restrict__ W2,
        const float* __restrict__ b2,
        float* __restrict__ ws, int use_wt) {
    const int b = blockIdx.x;
    const int j = threadIdx.x;           // 0..63
    const float sh = shapelet[j];
    if (b < EW) {
        const int e = b;
        float dot = sh * W2[e * LW + j];         // coalesced
        #pragma unroll
        for (int off = 32; off; off >>= 1) dot += __shfl_xor(dot, off, 64);
        if (use_wt) ws[WS_W1T + j * EW + e] = W1[e * LW + j];  // coalesced read
        if (j == 0) ws[e] = b1[e] - (dot + b2[e]);
    } else {
        float shn = __shfl_down(sh, 1, 64);
        float d = (j < LW - 1) ? (shn - sh) * (shn - sh) : 0.f;
        float q = sh * sh;
        #pragma unroll
        for (int off = 32; off; off >>= 1) {
            d += __shfl_xor(d, off, 64);
            q += __shfl_xor(q, off, 64);
        }
        if (j == 0) { ws[WS_SCI] = sqrtf(d + 0.001f); ws[WS_SS2] = q; }
    }
}

__global__ __launch_bounds__(64) void shapeblock_kernel(
        const float* __restrict__ x,
        const float* __restrict__ shapelet,
        const float* __restrict__ W1,
        const float* __restrict__ ws,
        float* __restrict__ out, int use_wt) {
    __shared__ __align__(16) float sp[SPPAD];

    const int b   = blockIdx.x;
    const int tid = threadIdx.x;   // one wave per block

    // ---- stage row: 157 float4, coalesced ----
    const float4* xr4 = (const float4*)(x + (size_t)b * XSTRIDE + XOFF);
    float4* sp4 = (float4*)sp;
    sp4[tid]      = xr4[tid];
    sp4[tid + 64] = xr4[tid + 64];
    if (tid < 29) sp4[tid + 128] = xr4[tid + 128];
    if (tid < SPPAD - T) sp[T + tid] = 0.f;     // zero pad 628..639
    const float s_ci = ws[WS_SCI];
    const float ss2  = ws[WS_SS2];
    __syncthreads();

    const int w0 = tid * WPT;

    // ---- streaming pass: corr for 9 windows + window-0 sums, via reg ring ----
    float ring[WPT], acc[WPT], head[WPT];
    #pragma unroll
    for (int i = 0; i < WPT; ++i) {
        ring[i] = sp[w0 + i];
        head[i] = ring[i];
        acc[i]  = 0.f;
    }
    float sd = 0.f, sw2 = 0.f, prev = 0.f;
    #pragma unroll
    for (int j = 0; j < LW; ++j) {
        const float sj = shapelet[j];     // uniform -> s_load (SGPR operand)
        const float v  = ring[j % WPT];   // = sp[w0 + j]
        sw2 = fmaf(v, v, sw2);
        if (j > 0) { float d = v - prev; sd = fmaf(d, d, sd); }
        prev = v;
        #pragma unroll
        for (int i = 0; i < WPT; ++i)
            acc[i] = fmaf(ring[(j + i) % WPT], sj, acc[i]);
        if (j < LW - 1) ring[j % WPT] = sp[w0 + j + WPT];
    }
    // invariant: ring[i] == sp[w0 + 63 + i]  (63 % 9 == 0), i = 0..8

    // ---- per-window CID + argmin key; O(1) slides from head/ring regs ----
    unsigned long long key = ~0ull;
    #pragma unroll
    for (int k = 0; k < WPT; ++k) {
        const int w = w0 + k;
        float pci = sqrtf(sd + 0.001f);
        float ed  = sqrtf(fmaxf(fmaf(-2.f, acc[k], sw2 + ss2), 0.f));
        float cf  = fminf(fmaxf(pci, s_ci) / fminf(pci, s_ci), 3.0f);
        float cid = ed * cf;
        if (w < NW) {
            unsigned long long kk =
                ((unsigned long long)__float_as_uint(cid) << 32) | (unsigned)w;
            key = kk < key ? kk : key;
        }
        if (k < WPT - 1) {
            float dold = head[k + 1] - head[k];
            float dnew = ring[k + 1] - ring[k];
            sd  = fmaf(dnew, dnew, fmaf(-dold, dold, sd));
            float vold = head[k], vnew = ring[k + 1];
            sw2 = fmaf(vnew, vnew, fmaf(-vold, vold, sw2));
        }
    }

    // ---- wave argmin butterfly ----
    #pragma unroll
    for (int off = 32; off; off >>= 1) {
        unsigned long long o =
            (unsigned long long)__shfl_xor((long long)key, off, 64);
        key = o < key ? o : key;
    }
    const int widx = (int)(key & 0xffffffffu);

    // ---- GEMV: out[b][e] = window . W1[e] + bias[e], e = tid, tid+64 ----
    float a0 = ws[tid];
    float a1 = ws[tid + 64];
    if (use_wt) {
        const float* wt = ws + WS_W1T;
        #pragma unroll
        for (int j = 0; j < LW; ++j) {
            float wv = sp[widx + j];                 // LDS broadcast
            a0 = fmaf(wv, wt[j * EW + tid], a0);     // coalesced L2
            a1 = fmaf(wv, wt[j * EW + 64 + tid], a1);
        }
    } else {
        #pragma unroll
        for (int j = 0; j < LW; ++j) {
            float wv = sp[widx + j];
            a0 = fmaf(wv, W1[tid * LW + j], a0);
            a1 = fmaf(wv, W1[(tid + 64) * LW + j], a1);
        }
    }
    out[(size_t)b * EW + tid]      = a0;
    out[(size_t)b * EW + tid + 64] = a1;
}

extern "C" void kernel_launch(void* const* d_in, const int* in_sizes, int n_in,
                              void* d_out, int out_size, void* d_ws, size_t ws_size,
                              hipStream_t stream) {
    const float* x        = (const float*)d_in[0];
    const float* shapelet = (const float*)d_in[1];
    const float* W1       = (const float*)d_in[2];
    const float* b1       = (const float*)d_in[3];
    const float* W2       = (const float*)d_in[4];
    const float* b2       = (const float*)d_in[5];
    float* out = (float*)d_out;
    float* ws  = (float*)d_ws;

    const int use_wt = (ws_size >= WS_NEEDED) ? 1 : 0;

    prep_kernel<<<EW + 1, 64, 0, stream>>>(shapelet, b1, W1, W2, b2, ws, use_wt);
    shapeblock_kernel<<<NB, 64, 0, stream>>>(x, shapelet, W1, ws, out, use_wt);
}